// Round 2
// baseline (410.745 us; speedup 1.0000x reference)
//
#include <hip/hip_runtime.h>

namespace {

constexpr int H  = 1080;
constexpr int W  = 1920;
constexpr int OH = 270;   // ceil(0.25 * 1080)
constexpr int OW = 480;   // ceil(0.25 * 1920)
constexpr int KT = 16;    // taps per output (P=18 minus 2 always-zero columns)

__global__ __launch_bounds__(256) void bicubic_k(
    const float* __restrict__ x,    // fp32, [BC, H, W]
    const float* __restrict__ wh,   // fp32, [OH, KT]
    const int*   __restrict__ ih,   // int32, [OH, KT]
    const float* __restrict__ ww,   // fp32, [OW, KT]
    const int*   __restrict__ iw,   // int32, [OW, KT]
    float*       __restrict__ out)  // fp32, [BC, OH, OW]
{
    const int ow = blockIdx.x * blockDim.x + threadIdx.x;
    const int oh = blockIdx.y;      // uniform per block -> scalar loads for wh/ih
    const int bc = blockIdx.z;
    if (ow >= OW) return;

    // horizontal weights for this output column (64B-aligned: ow*16 floats)
    float wt[KT];
    __builtin_memcpy(wt, ww + (size_t)ow * KT, KT * sizeof(float));

    // horizontal tap indices
    int ir[KT];
    __builtin_memcpy(ir, iw + (size_t)ow * KT, KT * sizeof(int));
    bool fast = true;
    #pragma unroll
    for (int k = 1; k < KT; ++k) fast = fast && (ir[k] == ir[0] + k);
    const int i0 = ir[0];

    const float* __restrict__ img = x + (size_t)bc * ((size_t)H * W);

    float acc = 0.0f;
    if (fast) {
        // contiguous 16-float (64B) window per row; 8B-aligned (i0 even)
        #pragma unroll
        for (int kh = 0; kh < KT; ++kh) {
            const int   r = ih[oh * KT + kh];
            const float w = wh[oh * KT + kh];
            float v[KT];
            __builtin_memcpy(v, img + (size_t)r * W + i0, KT * sizeof(float));
            float h = 0.0f;
            #pragma unroll
            for (int k = 0; k < KT; ++k) h = fmaf(v[k], wt[k], h);
            acc = fmaf(w, h, acc);
        }
    } else {
        // mirrored edges: scalar gather
        #pragma unroll 4
        for (int kh = 0; kh < KT; ++kh) {
            const int   r = ih[oh * KT + kh];
            const float w = wh[oh * KT + kh];
            const float* row = img + (size_t)r * W;
            float h = 0.0f;
            #pragma unroll
            for (int k = 0; k < KT; ++k) h = fmaf(row[ir[k]], wt[k], h);
            acc = fmaf(w, h, acc);
        }
    }

    out[((size_t)bc * OH + oh) * OW + ow] = acc;
}

// Safety net if tap count differs from the analytic K=16.
__global__ __launch_bounds__(256) void bicubic_generic(
    const float* __restrict__ x,
    const float* __restrict__ wh,
    const int*   __restrict__ ih,
    const float* __restrict__ ww,
    const int*   __restrict__ iw,
    float*       __restrict__ out,
    int Kh, int Kw, int total)
{
    int t = blockIdx.x * blockDim.x + threadIdx.x;
    if (t >= total) return;
    int ow = t % OW;
    int oh = (t / OW) % OH;
    int bc = t / (OW * OH);
    const float* img = x + (size_t)bc * ((size_t)H * W);
    float acc = 0.0f;
    for (int kh = 0; kh < Kh; ++kh) {
        const int   r = ih[oh * Kh + kh];
        const float w = wh[oh * Kh + kh];
        const float* row = img + (size_t)r * W;
        float h = 0.0f;
        for (int k = 0; k < Kw; ++k)
            h = fmaf(row[iw[ow * Kw + k]], ww[ow * Kw + k], h);
        acc = fmaf(w, h, acc);
    }
    out[t] = acc;
}

} // namespace

extern "C" void kernel_launch(void* const* d_in, const int* in_sizes, int n_in,
                              void* d_out, int out_size, void* d_ws, size_t ws_size,
                              hipStream_t stream) {
    const float* x  = (const float*)d_in[0];
    const float* wh = (const float*)d_in[1];
    const int*   ih = (const int*)d_in[2];
    const float* ww = (const float*)d_in[3];
    const int*   iw = (const int*)d_in[4];
    float*       out = (float*)d_out;

    const int BC = in_sizes[0] / (H * W);   // 24
    const int Kh = in_sizes[1] / OH;
    const int Kw = in_sizes[3] / OW;

    if (Kh == KT && Kw == KT) {
        dim3 grid((OW + 255) / 256, OH, BC);
        bicubic_k<<<grid, 256, 0, stream>>>(x, wh, ih, ww, iw, out);
    } else {
        int total = BC * OH * OW;
        bicubic_generic<<<(total + 255) / 256, 256, 0, stream>>>(
            x, wh, ih, ww, iw, out, Kh, Kw, total);
    }
}

// Round 3
// 341.101 us; speedup vs baseline: 1.2042x; 1.2042x over previous
//
#include <hip/hip_runtime.h>

namespace {

constexpr int H  = 1080;
constexpr int W  = 1920;
constexpr int OH = 270;   // ceil(0.25 * 1080)
constexpr int OW = 480;   // ceil(0.25 * 1920)
constexpr int KT = 16;    // taps per output (P=18 minus 2 always-zero columns)
constexpr int G  = 14;    // output rows per thread chunk; (OH-4) = 266 = 19*14
constexpr int NCH = 19;   // chunks covering oh = 2..267

// ---------------------------------------------------------------------------
// Main interior kernel: thread = (ow, chunk of G consecutive oh, bc).
// Streams the 4G+12 input rows once; 4 rolling accumulators (polyphase).
// Requires: interior taps contiguous (rows 4*oh-6.., cols 4*ow-6..), which
// holds for all oh in [2,268), ow in [2,478) at scale 1/4.
// ---------------------------------------------------------------------------
__global__ __launch_bounds__(256) void bicubic_main(
    const float* __restrict__ x,    // [BC, H, W]
    const float* __restrict__ wh,   // [OH, KT]
    const float* __restrict__ ww,   // [OW, KT]
    float*       __restrict__ out)  // [BC, OH, OW]
{
    const int ow = blockIdx.x * blockDim.x + threadIdx.x;
    if (ow < 2 || ow > OW - 3) return;          // edges handled by edge kernel
    const int oh0 = 2 + blockIdx.y * G;
    const int bc  = blockIdx.z;

    // column weights (identical for every interior ow by construction; read
    // this ow's own table row anyway)
    float wt[KT];
    __builtin_memcpy(wt, ww + (size_t)ow * KT, KT * sizeof(float));

    // row weights: all interior rows of wh are identical (d_j = 8.5 - j is
    // independent of the output index); use row oh0. Wave-uniform -> scalar.
    float wr[KT];
    __builtin_memcpy(wr, wh + (size_t)oh0 * KT, KT * sizeof(float));

    const int i0 = 4 * ow  - 6;                 // first column tap
    const int r0 = 4 * oh0 - 6;                 // first row tap of the chunk
    const float* __restrict__ base =
        x + (size_t)bc * ((size_t)H * W) + (size_t)r0 * W + i0;
    float* __restrict__ obase =
        out + ((size_t)bc * OH) * OW + ow;

    // rolling accumulators: a_m holds output row g = j - m
    float a0 = 0.f, a1 = 0.f, a2 = 0.f, a3 = 0.f;

    for (int j = 0; j < G + 3; ++j) {
        float h[4];
        #pragma unroll
        for (int p = 0; p < 4; ++p) {
            float v[KT];
            __builtin_memcpy(v, base + (size_t)(4 * j + p) * W,
                             KT * sizeof(float));
            // two partial chains for shorter dependency
            float s0 = 0.f, s1 = 0.f;
            #pragma unroll
            for (int k = 0; k < KT; k += 2) {
                s0 = fmaf(v[k],     wt[k],     s0);
                s1 = fmaf(v[k + 1], wt[k + 1], s1);
            }
            h[p] = s0 + s1;
        }
        #pragma unroll
        for (int p = 0; p < 4; ++p) {
            a0 = fmaf(wr[p],      h[p], a0);
            a1 = fmaf(wr[4 + p],  h[p], a1);
            a2 = fmaf(wr[8 + p],  h[p], a2);
            a3 = fmaf(wr[12 + p], h[p], a3);
        }
        if (j >= 3) obase[(size_t)(oh0 + j - 3) * OW] = a3;  // row complete
        a3 = a2; a2 = a1; a1 = a0; a0 = 0.f;                 // rotate
    }
}

// ---------------------------------------------------------------------------
// Edge kernel: per-pixel, fully table-driven (handles mirrored indices).
// Covers: oh in {0,1,OH-2,OH-1} x all ow   (4*480 px/bc)
//       + ow in {0,1,OW-2,OW-1} x oh in [2,OH-2)  (266*4 px/bc)
// ---------------------------------------------------------------------------
constexpr int EDGE_FULL = 4 * OW;             // 1920
constexpr int EDGE_TOT  = EDGE_FULL + (OH - 4) * 4;  // 1920 + 1064 = 2984

__global__ __launch_bounds__(256) void bicubic_edge(
    const float* __restrict__ x,
    const float* __restrict__ wh,
    const int*   __restrict__ ih,
    const float* __restrict__ ww,
    const int*   __restrict__ iw,
    float*       __restrict__ out)
{
    const int idx = blockIdx.x * blockDim.x + threadIdx.x;
    const int bc  = blockIdx.y;
    if (idx >= EDGE_TOT) return;

    int oh, ow;
    if (idx < EDGE_FULL) {
        int e = idx / OW;                     // 0..3
        ow = idx - e * OW;
        oh = (e < 2) ? e : OH - 4 + e;
    } else {
        int t = idx - EDGE_FULL;              // 0..1063
        int e = t & 3;
        oh = 2 + (t >> 2);
        ow = (e < 2) ? e : OW - 4 + e;
    }

    const float* __restrict__ img = x + (size_t)bc * ((size_t)H * W);

    float wt[KT];
    __builtin_memcpy(wt, ww + (size_t)ow * KT, KT * sizeof(float));
    int ir[KT];
    __builtin_memcpy(ir, iw + (size_t)ow * KT, KT * sizeof(int));

    bool fast = true;
    #pragma unroll
    for (int k = 1; k < KT; ++k) fast = fast && (ir[k] == ir[0] + k);
    const int i0 = ir[0];

    float acc = 0.0f;
    #pragma unroll 4
    for (int kh = 0; kh < KT; ++kh) {
        const int   r = ih[oh * KT + kh];
        const float w = wh[oh * KT + kh];
        const float* row = img + (size_t)r * W;
        float h = 0.0f;
        if (fast) {
            float v[KT];
            __builtin_memcpy(v, row + i0, KT * sizeof(float));
            #pragma unroll
            for (int k = 0; k < KT; ++k) h = fmaf(v[k], wt[k], h);
        } else {
            #pragma unroll
            for (int k = 0; k < KT; ++k) h = fmaf(row[ir[k]], wt[k], h);
        }
        acc = fmaf(w, h, acc);
    }
    out[((size_t)bc * OH + oh) * OW + ow] = acc;
}

// ---------------------------------------------------------------------------
// Safety net if tap count differs from the analytic K=16 (generic per-pixel).
// ---------------------------------------------------------------------------
__global__ __launch_bounds__(256) void bicubic_generic(
    const float* __restrict__ x,
    const float* __restrict__ wh,
    const int*   __restrict__ ih,
    const float* __restrict__ ww,
    const int*   __restrict__ iw,
    float*       __restrict__ out,
    int Kh, int Kw, int total)
{
    int t = blockIdx.x * blockDim.x + threadIdx.x;
    if (t >= total) return;
    int ow = t % OW;
    int oh = (t / OW) % OH;
    int bc = t / (OW * OH);
    const float* img = x + (size_t)bc * ((size_t)H * W);
    float acc = 0.0f;
    for (int kh = 0; kh < Kh; ++kh) {
        const int   r = ih[oh * Kh + kh];
        const float w = wh[oh * Kh + kh];
        const float* row = img + (size_t)r * W;
        float h = 0.0f;
        for (int k = 0; k < Kw; ++k)
            h = fmaf(row[iw[ow * Kw + k]], ww[ow * Kw + k], h);
        acc = fmaf(w, h, acc);
    }
    out[t] = acc;
}

} // namespace

extern "C" void kernel_launch(void* const* d_in, const int* in_sizes, int n_in,
                              void* d_out, int out_size, void* d_ws, size_t ws_size,
                              hipStream_t stream) {
    const float* x  = (const float*)d_in[0];
    const float* wh = (const float*)d_in[1];
    const int*   ih = (const int*)d_in[2];
    const float* ww = (const float*)d_in[3];
    const int*   iw = (const int*)d_in[4];
    float*       out = (float*)d_out;

    const int BC = in_sizes[0] / (H * W);   // 24
    const int Kh = in_sizes[1] / OH;
    const int Kw = in_sizes[3] / OW;

    if (Kh == KT && Kw == KT) {
        // interior: oh 2..267 in 19 chunks of G=14; ow 2..477
        dim3 mg((OW + 255) / 256, NCH, BC);
        bicubic_main<<<mg, 256, 0, stream>>>(x, wh, ww, out);
        // edges: table-driven gather
        dim3 eg((EDGE_TOT + 255) / 256, BC, 1);
        bicubic_edge<<<eg, 256, 0, stream>>>(x, wh, ih, ww, iw, out);
    } else {
        int total = BC * OH * OW;
        bicubic_generic<<<(total + 255) / 256, 256, 0, stream>>>(
            x, wh, ih, ww, iw, out, Kh, Kw, total);
    }
}

// Round 4
// 325.449 us; speedup vs baseline: 1.2621x; 1.0481x over previous
//
#include <hip/hip_runtime.h>

namespace {

constexpr int H  = 1080;
constexpr int W  = 1920;
constexpr int OH = 270;    // ceil(0.25 * 1080)
constexpr int OW = 480;    // ceil(0.25 * 1920)
constexpr int KT = 16;     // taps per output
constexpr int G  = 7;      // output rows per chunk; oh 2..267 in 38 chunks
constexpr int NCHUNK = 38;
constexpr int COLS = 1024;     // staged input cols per block (256 thr x 4)
constexpr int VSTRIDE = 1028;  // vbuf row stride in floats (pad 4)

// ---------------------------------------------------------------------------
// Fused interior kernel.
// Step 1 (vertical): thread owns 4 consecutive input cols; streams 4G+12=40
//   rows with unit-lane-stride loads; polyphase rolling accumulators; writes
//   vertically-downsampled rows into LDS vbuf[G][COLS].
// Step 2 (horizontal): thread = one output col; 16-float window from vbuf via
//   4x ds_read_b128; coalesced store.
// Valid for oh in [2,268), ow in [2,478): taps contiguous (validated R3).
// ---------------------------------------------------------------------------
__global__ __launch_bounds__(256) void bicubic_tile(
    const float* __restrict__ x,    // [BC, H, W]
    const float* __restrict__ wh,   // [OH, KT]
    const float* __restrict__ ww,   // [OW, KT]
    float*       __restrict__ out)  // [BC, OH, OW]
{
    __shared__ float vbuf[G * VSTRIDE];   // 28.8 KB

    const int tid  = threadIdx.x;
    const int tile = blockIdx.x;                 // 0..1
    const int oh0  = 2 + G * blockIdx.y;         // 2..261
    const int bc   = blockIdx.z;

    const int ow_base = (tile == 0) ? 2   : 255;
    const int Nw      = (tile == 0) ? 253 : 223;
    const int c0      = 4 * ow_base - 6;         // first staged input col
    const int r0      = 4 * oh0 - 6;             // first input row

    // vertical weights: wh rows identical for interior rows (validated R3);
    // oh0 is wave-uniform -> scalar loads
    float wr[KT];
    __builtin_memcpy(wr, wh + (size_t)oh0 * KT, sizeof(wr));

    // this thread's 4 input columns (clamped inside the image; clamped
    // duplicates land in vbuf slots never read by a valid output)
    int c = c0 + 4 * tid;
    if (c > W - 4) c = W - 4;
    const float* __restrict__ col = x + ((size_t)bc * H + (size_t)r0) * W + c;

    float acc[4][4];
    #pragma unroll
    for (int m = 0; m < 4; ++m)
        #pragma unroll
        for (int cc = 0; cc < 4; ++cc) acc[m][cc] = 0.0f;

    for (int q = 0; q < G + 3; ++q) {
        #pragma unroll
        for (int p = 0; p < 4; ++p) {
            float v[4];
            __builtin_memcpy(v, col + (size_t)(4 * q + p) * W, 16);
            #pragma unroll
            for (int cc = 0; cc < 4; ++cc) {
                acc[0][cc] = fmaf(wr[p],      v[cc], acc[0][cc]);
                acc[1][cc] = fmaf(wr[4 + p],  v[cc], acc[1][cc]);
                acc[2][cc] = fmaf(wr[8 + p],  v[cc], acc[2][cc]);
                acc[3][cc] = fmaf(wr[12 + p], v[cc], acc[3][cc]);
            }
        }
        if (q >= 3) {
            // output row t = q-3 complete in acc[3]; 16B-aligned ds_write_b128
            __builtin_memcpy(&vbuf[(q - 3) * VSTRIDE + 4 * tid], acc[3], 16);
        }
        #pragma unroll
        for (int cc = 0; cc < 4; ++cc) {
            acc[3][cc] = acc[2][cc];
            acc[2][cc] = acc[1][cc];
            acc[1][cc] = acc[0][cc];
            acc[0][cc] = 0.0f;
        }
    }
    __syncthreads();

    // -------- horizontal pass --------
    if (tid < Nw) {
        const int ow = ow_base + tid;
        float wt[KT];
        __builtin_memcpy(wt, ww + (size_t)ow * KT, sizeof(wt));
        float* __restrict__ obase =
            out + ((size_t)bc * OH + oh0) * OW + ow;
        #pragma unroll
        for (int t = 0; t < G; ++t) {
            float v[KT];
            __builtin_memcpy(v, &vbuf[t * VSTRIDE + 4 * tid], sizeof(v));
            float s0 = 0.f, s1 = 0.f;
            #pragma unroll
            for (int k = 0; k < KT; k += 2) {
                s0 = fmaf(v[k],     wt[k],     s0);
                s1 = fmaf(v[k + 1], wt[k + 1], s1);
            }
            obase[(size_t)t * OW] = s0 + s1;
        }
    }
}

// ---------------------------------------------------------------------------
// Edge kernel (validated R3): oh in {0,1,268,269} x all ow, plus
// ow in {0,1,478,479} x oh in [2,268).
// ---------------------------------------------------------------------------
constexpr int EDGE_FULL = 4 * OW;                    // 1920
constexpr int EDGE_TOT  = EDGE_FULL + (OH - 4) * 4;  // 2984

__global__ __launch_bounds__(256) void bicubic_edge(
    const float* __restrict__ x,
    const float* __restrict__ wh,
    const int*   __restrict__ ih,
    const float* __restrict__ ww,
    const int*   __restrict__ iw,
    float*       __restrict__ out)
{
    const int idx = blockIdx.x * blockDim.x + threadIdx.x;
    const int bc  = blockIdx.y;
    if (idx >= EDGE_TOT) return;

    int oh, ow;
    if (idx < EDGE_FULL) {
        int e = idx / OW;
        ow = idx - e * OW;
        oh = (e < 2) ? e : OH - 4 + e;
    } else {
        int t = idx - EDGE_FULL;
        int e = t & 3;
        oh = 2 + (t >> 2);
        ow = (e < 2) ? e : OW - 4 + e;
    }

    const float* __restrict__ img = x + (size_t)bc * ((size_t)H * W);

    float wt[KT];
    __builtin_memcpy(wt, ww + (size_t)ow * KT, sizeof(wt));
    int ir[KT];
    __builtin_memcpy(ir, iw + (size_t)ow * KT, sizeof(ir));

    bool fast = true;
    #pragma unroll
    for (int k = 1; k < KT; ++k) fast = fast && (ir[k] == ir[0] + k);
    const int i0 = ir[0];

    float acc = 0.0f;
    #pragma unroll 4
    for (int kh = 0; kh < KT; ++kh) {
        const int   r = ih[oh * KT + kh];
        const float w = wh[oh * KT + kh];
        const float* row = img + (size_t)r * W;
        float h = 0.0f;
        if (fast) {
            float v[KT];
            __builtin_memcpy(v, row + i0, sizeof(v));
            #pragma unroll
            for (int k = 0; k < KT; ++k) h = fmaf(v[k], wt[k], h);
        } else {
            #pragma unroll
            for (int k = 0; k < KT; ++k) h = fmaf(row[ir[k]], wt[k], h);
        }
        acc = fmaf(w, h, acc);
    }
    out[((size_t)bc * OH + oh) * OW + ow] = acc;
}

// ---------------------------------------------------------------------------
// Safety net for unexpected tap counts.
// ---------------------------------------------------------------------------
__global__ __launch_bounds__(256) void bicubic_generic(
    const float* __restrict__ x,
    const float* __restrict__ wh,
    const int*   __restrict__ ih,
    const float* __restrict__ ww,
    const int*   __restrict__ iw,
    float*       __restrict__ out,
    int Kh, int Kw, int total)
{
    int t = blockIdx.x * blockDim.x + threadIdx.x;
    if (t >= total) return;
    int ow = t % OW;
    int oh = (t / OW) % OH;
    int bc = t / (OW * OH);
    const float* img = x + (size_t)bc * ((size_t)H * W);
    float acc = 0.0f;
    for (int kh = 0; kh < Kh; ++kh) {
        const int   r = ih[oh * Kh + kh];
        const float w = wh[oh * Kh + kh];
        const float* row = img + (size_t)r * W;
        float h = 0.0f;
        for (int k = 0; k < Kw; ++k)
            h = fmaf(row[iw[ow * Kw + k]], ww[ow * Kw + k], h);
        acc = fmaf(w, h, acc);
    }
    out[t] = acc;
}

} // namespace

extern "C" void kernel_launch(void* const* d_in, const int* in_sizes, int n_in,
                              void* d_out, int out_size, void* d_ws, size_t ws_size,
                              hipStream_t stream) {
    const float* x  = (const float*)d_in[0];
    const float* wh = (const float*)d_in[1];
    const int*   ih = (const int*)d_in[2];
    const float* ww = (const float*)d_in[3];
    const int*   iw = (const int*)d_in[4];
    float*       out = (float*)d_out;

    const int BC = in_sizes[0] / (H * W);   // 24
    const int Kh = in_sizes[1] / OH;
    const int Kw = in_sizes[3] / OW;

    if (Kh == KT && Kw == KT) {
        dim3 mg(2, NCHUNK, BC);
        bicubic_tile<<<mg, 256, 0, stream>>>(x, wh, ww, out);
        dim3 eg((EDGE_TOT + 255) / 256, BC, 1);
        bicubic_edge<<<eg, 256, 0, stream>>>(x, wh, ih, ww, iw, out);
    } else {
        int total = BC * OH * OW;
        bicubic_generic<<<(total + 255) / 256, 256, 0, stream>>>(
            x, wh, ih, ww, iw, out, Kh, Kw, total);
    }
}